// Round 2
// baseline (684.842 us; speedup 1.0000x reference)
//
#include <hip/hip_runtime.h>
#include <math.h>

#define NK 512
#define DD 256
#define NB 32
#define NT 4096

typedef __attribute__((ext_vector_type(8))) short bf16x8;
typedef __attribute__((ext_vector_type(4))) float f32x4;

#define MARGIN 1.5e-4f

// ---------------------------------------------------------------------------
// bf16 RNE split: x = hi + lo + O(2^-18 x)
// ---------------------------------------------------------------------------
__device__ __forceinline__ void bsplit(float x, unsigned short& h, unsigned short& l) {
    unsigned int u = __float_as_uint(x);
    unsigned int r = u + 0x7fffu + ((u >> 16) & 1u);
    h = (unsigned short)(r >> 16);
    float hf = __uint_as_float(((unsigned int)h) << 16);
    float res = x - hf;
    unsigned int u2 = __float_as_uint(res);
    unsigned int r2 = u2 + 0x7fffu + ((u2 >> 16) & 1u);
    l = (unsigned short)(r2 >> 16);
}

// ---------------------------------------------------------------------------
// wsq[k] = sum_d W[k][d]^2, fp64 accumulated, rounded once to fp32.
// ---------------------------------------------------------------------------
__global__ __launch_bounds__(256) void wsq_kernel(const float* __restrict__ W,
                                                  float* __restrict__ wsq) {
    int k = blockIdx.x * blockDim.x + threadIdx.x;
    if (k >= NK) return;
    const float4* row = (const float4*)(W + (size_t)k * DD);
    double s = 0.0;
    #pragma unroll 8
    for (int i = 0; i < DD / 4; ++i) {
        float4 v = row[i];
        s += (double)v.x * v.x + (double)v.y * v.y + (double)v.z * v.z + (double)v.w * v.w;
    }
    wsq[k] = (float)s;
}

// ---------------------------------------------------------------------------
// W'' prekernel: bf16-split W into the exact [c_all][j][tid][16B] order phase-1
// consumes. Slot s of k'=3d+s: s=0 -> wh, s=1 -> wl, s=2 -> wh.
// grid 32 (= ktile*8 + chunk), 256 threads.
// ---------------------------------------------------------------------------
__global__ __launch_bounds__(256) void convw_kernel(const float* __restrict__ W,
                                                    int4* __restrict__ Wpp) {
    const int bx  = blockIdx.x;         // c_all = kt*8 + c
    const int kt  = bx >> 3;
    const int c   = bx & 7;
    const int tid = threadIdx.x;
    const int n_l = tid & 127;
    const int g   = tid >> 7;
    const int k   = kt * 128 + n_l;
    const int dbase = c * 32 + g * 16;  // (c*96+g*48)/3

    unsigned short outv[48];
    #pragma unroll
    for (int e = 0; e < 48; ++e) {
        int d = dbase + e / 3;
        int s = e % 3;
        float wv = W[(size_t)k * DD + d];
        unsigned short h, l;
        bsplit(wv, h, l);
        outv[e] = (s == 1) ? l : h;
    }
    unsigned int u[12];
    #pragma unroll
    for (int q = 0; q < 12; ++q)
        u[q] = (unsigned int)outv[4 * q] | ((unsigned int)outv[4 * q + 1] << 16);
    // NOTE: the above packs pairs (2q,2q+1); rewrite properly below.
    #pragma unroll
    for (int q = 0; q < 12; ++q)
        u[q] = (unsigned int)outv[2 * q] | ((unsigned int)outv[2 * q + 1] << 16);
    int4* up = (int4*)u;
    #pragma unroll
    for (int j = 0; j < 3; ++j)
        Wpp[(size_t)(bx * 6 + j) * 256 + tid] = up[j];
    unsigned int u2[12];
    #pragma unroll
    for (int q = 0; q < 12; ++q)
        u2[q] = (unsigned int)outv[24 + 2 * q] | ((unsigned int)outv[24 + 2 * q + 1] << 16);
    int4* up2 = (int4*)u2;
    #pragma unroll
    for (int j = 0; j < 3; ++j)
        Wpp[(size_t)(bx * 6 + 3 + j) * 256 + tid] = up2[j];
}

// ---------------------------------------------------------------------------
// Phase 1: MFMA bf16-split GEMM. Block = 128 t x 128 codes, 256 thr (4 waves,
// each 64x64 as 4x4 tiles of 16x16x32_bf16). K' = 768 in 8 chunks of 96.
// Emits per (t, ktile): (q1, i1, q2) after the reference rounding chain.
// ---------------------------------------------------------------------------
__global__ __launch_bounds__(256, 3) void vq_phase1(const float* __restrict__ Z,
                                                    const int4* __restrict__ Wpp,
                                                    const float* __restrict__ wsq,
                                                    float* __restrict__ gq1,
                                                    float* __restrict__ gq2,
                                                    int* __restrict__ gi1) {
    __shared__ short As[128 * 104];   // 26624 B, rows = t (pad 104 -> 208 B)
    __shared__ short Bs[128 * 104];   // 26624 B, rows = n (code)

    const int tid  = threadIdx.x;
    const int wave = tid >> 6;
    const int lane = tid & 63;
    const int lm   = lane & 15;
    const int lq   = lane >> 4;
    const int mw   = wave & 1;
    const int nw   = wave >> 1;

    const int bx = blockIdx.x;
    const int kt = bx & 3;
    const int tl = bx >> 2;
    const int b  = tl >> 5;
    const int t0 = (tl & 31) * 128;

    const int t_l = tid & 127;
    const int dg  = tid >> 7;

    const float* zcol = Z + (size_t)b * DD * NT + t0 + t_l;

    f32x4 acc[4][4];
    #pragma unroll
    for (int mt = 0; mt < 4; ++mt)
        #pragma unroll
        for (int nt = 0; nt < 4; ++nt)
            acc[mt][nt] = (f32x4){0.f, 0.f, 0.f, 0.f};

    double zacc = 0.0;

    for (int c = 0; c < 8; ++c) {
        const int d0 = c * 32;
        __syncthreads();   // previous chunk's readers done

        // ---- A staging: load 16 z (coalesced per-d), fp64 zsq, split, pack
        float zv[16];
        #pragma unroll
        for (int j = 0; j < 16; ++j)
            zv[j] = zcol[(size_t)(d0 + dg * 16 + j) * NT];
        #pragma unroll
        for (int j = 0; j < 16; ++j)
            zacc = fma((double)zv[j], (double)zv[j], zacc);
        unsigned short h[16], l[16];
        #pragma unroll
        for (int j = 0; j < 16; ++j) bsplit(zv[j], h[j], l[j]);

        #pragma unroll
        for (int g2 = 0; g2 < 2; ++g2) {
            const int j0 = g2 * 8;
            unsigned int u[12];
            #pragma unroll
            for (int cc = 0; cc < 4; ++cc) {
                int j = j0 + 2 * cc;
                u[3 * cc + 0] = (unsigned int)h[j] | ((unsigned int)h[j] << 16);
                u[3 * cc + 1] = (unsigned int)l[j] | ((unsigned int)h[j + 1] << 16);
                u[3 * cc + 2] = (unsigned int)h[j + 1] | ((unsigned int)l[j + 1] << 16);
            }
            int4* dst = (int4*)&As[t_l * 104 + dg * 48 + g2 * 24];
            int4* us  = (int4*)u;
            dst[0] = us[0]; dst[1] = us[1]; dst[2] = us[2];
        }

        // ---- B staging: 6 x dwordx4 from precomputed W'' -> padded LDS rows
        {
            const int c_all = kt * 8 + c;
            int4 v[6];
            #pragma unroll
            for (int j = 0; j < 6; ++j)
                v[j] = Wpp[(size_t)(c_all * 6 + j) * 256 + tid];
            int4* dst = (int4*)&Bs[t_l * 104 + dg * 48];  // row n = tid&127
            #pragma unroll
            for (int j = 0; j < 6; ++j) dst[j] = v[j];
        }
        __syncthreads();

        // ---- MFMA: 3 K-steps of 32 over the 96-wide chunk
        #pragma unroll
        for (int ks = 0; ks < 3; ++ks) {
            bf16x8 a[4], bb[4];
            #pragma unroll
            for (int mt = 0; mt < 4; ++mt)
                a[mt] = *(const bf16x8*)&As[(mw * 64 + mt * 16 + lm) * 104 + ks * 32 + lq * 8];
            #pragma unroll
            for (int nt = 0; nt < 4; ++nt)
                bb[nt] = *(const bf16x8*)&Bs[(nw * 64 + nt * 16 + lm) * 104 + ks * 32 + lq * 8];
            #pragma unroll
            for (int mt = 0; mt < 4; ++mt)
                #pragma unroll
                for (int nt = 0; nt < 4; ++nt)
                    acc[mt][nt] = __builtin_amdgcn_mfma_f32_16x16x32_bf16(
                        a[mt], bb[nt], acc[mt][nt], 0, 0, 0);
        }
    }

    // ---- epilogue: zsq reduce, rounding chain, per-t top-2 argmin
    __syncthreads();
    double* zred = (double*)As;
    zred[dg * 128 + t_l] = zacc;
    __syncthreads();
    float* zf = (float*)Bs;
    if (tid < 128) zf[tid] = (float)(zred[tid] + zred[128 + tid]);
    __syncthreads();

    float wq[4];
    #pragma unroll
    for (int nt = 0; nt < 4; ++nt)
        wq[nt] = wsq[kt * 128 + nw * 64 + nt * 16 + lm];

    float* cb1 = (float*)As;
    float* cb2 = (float*)As + 256;
    int*   cbi = (int*)((float*)As + 512);
    const int kbase = kt * 128 + nw * 64 + lm;

    #pragma unroll
    for (int mt = 0; mt < 4; ++mt) {
        #pragma unroll
        for (int r = 0; r < 4; ++r) {
            float zz = zf[mw * 64 + mt * 16 + lq * 4 + r];
            float q1 = INFINITY, q2 = INFINITY;
            int i1 = 0x7fffffff;
            #pragma unroll
            for (int nt = 0; nt < 4; ++nt) {
                float dist = __fadd_rn(__fsub_rn(zz, __fmul_rn(2.0f, acc[mt][nt][r])), wq[nt]);
                int kk = kbase + nt * 16;
                if (dist < q1 || (dist == q1 && kk < i1)) { q2 = q1; q1 = dist; i1 = kk; }
                else if (dist < q2) q2 = dist;
            }
            #pragma unroll
            for (int mk = 1; mk <= 8; mk <<= 1) {
                float o1 = __shfl_xor(q1, mk);
                float o2 = __shfl_xor(q2, mk);
                int   oi = __shfl_xor(i1, mk);
                if (o1 < q1 || (o1 == q1 && oi < i1)) { q2 = fminf(q1, o2); q1 = o1; i1 = oi; }
                else { q2 = fminf(o1, q2); }
            }
            if (lm == 0) {
                int m = mw * 64 + mt * 16 + lq * 4 + r;
                cb1[m * 2 + nw] = q1;
                cb2[m * 2 + nw] = q2;
                cbi[m * 2 + nw] = i1;
            }
        }
    }
    __syncthreads();
    if (tid < 128) {
        float a1 = cb1[tid * 2],     a2 = cb2[tid * 2];     int ai = cbi[tid * 2];
        float b1 = cb1[tid * 2 + 1], b2 = cb2[tid * 2 + 1]; int bi = cbi[tid * 2 + 1];
        float q1, q2; int i1;
        if (b1 < a1 || (b1 == a1 && bi < ai)) { q1 = b1; i1 = bi; q2 = fminf(a1, b2); }
        else { q1 = a1; i1 = ai; q2 = fminf(b1, a2); }
        size_t btg = (size_t)b * NT + t0 + tid;
        gq1[btg * 4 + kt] = q1;
        gq2[btg * 4 + kt] = q2;
        gi1[btg * 4 + kt] = i1;
    }
}

// ---------------------------------------------------------------------------
// Phase 2: merge k-tiles; safe outputs written directly, near-tie outputs
// recomputed exactly (same rounding chain as the R1-passing kernel).
// ---------------------------------------------------------------------------
__global__ __launch_bounds__(256) void vq_phase2(const float* __restrict__ Z,
                                                 const float* __restrict__ W,
                                                 const float* __restrict__ wsq,
                                                 const float* __restrict__ gq1,
                                                 const float* __restrict__ gq2,
                                                 const int* __restrict__ gi1,
                                                 int* __restrict__ out) {
    const int bt   = blockIdx.x * 256 + threadIdx.x;
    const int lane = threadIdx.x & 63;

    float q1 = INFINITY, q2 = INFINITY;
    int i1 = 0x7fffffff;
    #pragma unroll
    for (int kt = 0; kt < 4; ++kt) {
        float o1 = gq1[(size_t)bt * 4 + kt];
        float o2 = gq2[(size_t)bt * 4 + kt];
        int   oi = gi1[(size_t)bt * 4 + kt];
        if (o1 < q1 || (o1 == q1 && oi < i1)) { q2 = fminf(q1, o2); q1 = o1; i1 = oi; }
        else { q2 = fminf(o1, q2); }
    }
    bool flag = (q2 - q1) <= MARGIN;
    if (!flag) out[bt] = i1;

    unsigned long long mball = __ballot(flag);
    while (mball) {
        int src = __ffsll((long long)mball) - 1;
        mball &= mball - 1;
        int tbt = __shfl(bt, src);
        int b = tbt >> 12;
        int t = tbt & 4095;
        const float* zp = Z + (size_t)b * DD * NT + t;

        double zs = 0.0;
        for (int d = 0; d < DD; ++d) {
            double zv = (double)zp[(size_t)d * NT];
            zs = fma(zv, zv, zs);
        }
        float zsf = (float)zs;

        float accs[8];
        #pragma unroll
        for (int g = 0; g < 8; ++g) accs[g] = 0.f;
        for (int d = 0; d < DD; ++d) {
            float zv = zp[(size_t)d * NT];
            #pragma unroll
            for (int g = 0; g < 8; ++g)
                accs[g] = fmaf(zv, W[(size_t)(lane + g * 64) * DD + d], accs[g]);
        }
        float bq = INFINITY;
        int bi = 0x7fffffff;
        #pragma unroll
        for (int g = 0; g < 8; ++g) {
            int kk = lane + g * 64;
            float dist = __fadd_rn(__fsub_rn(zsf, __fmul_rn(2.0f, accs[g])), wsq[kk]);
            if (dist < bq || (dist == bq && kk < bi)) { bq = dist; bi = kk; }
        }
        #pragma unroll
        for (int mk = 1; mk <= 32; mk <<= 1) {
            float ov = __shfl_xor(bq, mk);
            int   oi = __shfl_xor(bi, mk);
            if (ov < bq || (ov == bq && oi < bi)) { bq = ov; bi = oi; }
        }
        if (lane == 0) out[tbt] = bi;
    }
}

// ---------------------------------------------------------------------------
// Fallback (R1 kernel) if ws is too small for the MFMA path.
// ---------------------------------------------------------------------------
#define BT 128
#define BK 128
#define DCHUNK 32
#define NKC (NK / BK)
#define NDC (DD / DCHUNK)
#define WSTR (BK + 4)

__global__ __launch_bounds__(256) void vq_fallback(const float* __restrict__ Z,
                                                   const float* __restrict__ W,
                                                   const float* __restrict__ wsq_g,
                                                   int* __restrict__ out) {
    __shared__ __align__(16) float Zs[DCHUNK * BT];
    __shared__ __align__(16) float Ws[DCHUNK * WSTR];
    __shared__ float wsqs[NK];

    const int tid = threadIdx.x;
    const int tx  = tid & 15;
    const int ty  = tid >> 4;
    const int b   = blockIdx.y;
    const int t0  = blockIdx.x * BT;

    if (wsq_g) {
        wsqs[tid]       = wsq_g[tid];
        wsqs[tid + 256] = wsq_g[tid + 256];
    } else {
        for (int k = tid; k < NK; k += 256) {
            const float4* row = (const float4*)(W + (size_t)k * DD);
            double s = 0.0;
            for (int i = 0; i < DD / 4; ++i) {
                float4 v = row[i];
                s += (double)v.x * v.x + (double)v.y * v.y + (double)v.z * v.z + (double)v.w * v.w;
            }
            wsqs[k] = (float)s;
        }
    }

    const float* Zb = Z + (size_t)b * DD * NT + t0;

    float best[8]; int bidx[8];
    #pragma unroll
    for (int a = 0; a < 8; ++a) { best[a] = INFINITY; bidx[a] = 0x7fffffff; }
    double zsqd[8];
    #pragma unroll
    for (int a = 0; a < 8; ++a) zsqd[a] = 0.0;
    float zsqf[8];

    for (int kc = 0; kc < NKC; ++kc) {
        float acc[8][8];
        #pragma unroll
        for (int a = 0; a < 8; ++a)
            #pragma unroll
            for (int c = 0; c < 8; ++c) acc[a][c] = 0.f;

        for (int dc = 0; dc < NDC; ++dc) {
            const int d0 = dc * DCHUNK;
            __syncthreads();
            #pragma unroll
            for (int i = 0; i < 4; ++i) {
                int f  = tid + i * 256;
                int r  = f >> 5;
                int c4 = f & 31;
                float4 v = *(const float4*)(Zb + (size_t)(d0 + r) * NT + c4 * 4);
                *(float4*)(&Zs[r * BT + c4 * 4]) = v;
            }
            #pragma unroll
            for (int i = 0; i < 4; ++i) {
                int u  = tid + i * 256;
                int k  = u >> 3;
                int rg = u & 7;
                float4 v = *(const float4*)(W + (size_t)(kc * BK + k) * DD + d0 + rg * 4);
                Ws[(rg * 4 + 0) * WSTR + k] = v.x;
                Ws[(rg * 4 + 1) * WSTR + k] = v.y;
                Ws[(rg * 4 + 2) * WSTR + k] = v.z;
                Ws[(rg * 4 + 3) * WSTR + k] = v.w;
            }
            __syncthreads();
            #pragma unroll 4
            for (int d = 0; d < DCHUNK; ++d) {
                float4 z0 = *(const float4*)(&Zs[d * BT + ty * 8]);
                float4 z1 = *(const float4*)(&Zs[d * BT + ty * 8 + 4]);
                float4 w0 = *(const float4*)(&Ws[d * WSTR + tx * 8]);
                float4 w1 = *(const float4*)(&Ws[d * WSTR + tx * 8 + 4]);
                float za[8] = {z0.x, z0.y, z0.z, z0.w, z1.x, z1.y, z1.z, z1.w};
                float wa[8] = {w0.x, w0.y, w0.z, w0.w, w1.x, w1.y, w1.z, w1.w};
                if (kc == 0) {
                    #pragma unroll
                    for (int a = 0; a < 8; ++a)
                        zsqd[a] = fma((double)za[a], (double)za[a], zsqd[a]);
                }
                #pragma unroll
                for (int a = 0; a < 8; ++a)
                    #pragma unroll
                    for (int c = 0; c < 8; ++c)
                        acc[a][c] = fmaf(za[a], wa[c], acc[a][c]);
            }
        }
        if (kc == 0) {
            #pragma unroll
            for (int a = 0; a < 8; ++a) zsqf[a] = (float)zsqd[a];
        }
        #pragma unroll
        for (int c = 0; c < 8; ++c) {
            int   kg = kc * BK + tx * 8 + c;
            float wqv = wsqs[kg];
            #pragma unroll
            for (int a = 0; a < 8; ++a) {
                float c2   = __fmul_rn(2.0f, acc[a][c]);
                float s    = __fsub_rn(zsqf[a], c2);
                float dist = __fadd_rn(s, wqv);
                if (dist < best[a] || (dist == best[a] && kg < bidx[a])) {
                    best[a] = dist; bidx[a] = kg;
                }
            }
        }
    }
    __syncthreads();
    float* redv = Zs;
    int*   redi = (int*)Ws;
    #pragma unroll
    for (int a = 0; a < 8; ++a) {
        int tl2 = ty * 8 + a;
        redv[tl2 * 16 + tx] = best[a];
        redi[tl2 * 16 + tx] = bidx[a];
    }
    __syncthreads();
    if (tid < BT) {
        float bv = INFINITY; int bi = 0x7fffffff;
        #pragma unroll
        for (int j = 0; j < 16; ++j) {
            float v = redv[tid * 16 + j];
            int   i = redi[tid * 16 + j];
            if (v < bv || (v == bv && i < bi)) { bv = v; bi = i; }
        }
        out[(size_t)b * NT + t0 + tid] = bi;
    }
}

extern "C" void kernel_launch(void* const* d_in, const int* in_sizes, int n_in,
                              void* d_out, int out_size, void* d_ws, size_t ws_size,
                              hipStream_t stream) {
    const float* Z = (const float*)d_in[0];   // [B, D, T]
    const float* W = (const float*)d_in[1];   // [K, D]
    int* out = (int*)d_out;                   // [B, T]

    const size_t NEED = 2048 + 786432 + 3ull * 2097152;  // 7,079,936 B
    if (ws_size >= NEED) {
        float* wsq = (float*)d_ws;
        int4* wpp  = (int4*)((char*)d_ws + 2048);
        float* cq1 = (float*)((char*)d_ws + 2048 + 786432);
        float* cq2 = cq1 + 524288;
        int*   ci1 = (int*)(cq2 + 524288);

        wsq_kernel<<<dim3(2), dim3(256), 0, stream>>>(W, wsq);
        convw_kernel<<<dim3(32), dim3(256), 0, stream>>>(W, wpp);
        vq_phase1<<<dim3(4096), dim3(256), 0, stream>>>(Z, wpp, wsq, cq1, cq2, ci1);
        vq_phase2<<<dim3(512), dim3(256), 0, stream>>>(Z, W, wsq, cq1, cq2, ci1, out);
    } else {
        float* wsq = nullptr;
        if (ws_size >= NK * sizeof(float)) {
            wsq = (float*)d_ws;
            wsq_kernel<<<dim3(2), dim3(256), 0, stream>>>(W, wsq);
        }
        vq_fallback<<<dim3(NT / BT, NB), dim3(256), 0, stream>>>(Z, W, wsq, out);
    }
}

// Round 4
// 406.662 us; speedup vs baseline: 1.6841x; 1.6841x over previous
//
#include <hip/hip_runtime.h>
#include <math.h>

#define NK 512
#define DD 256
#define NB 32
#define NT 4096

typedef __attribute__((ext_vector_type(8))) short bf16x8;
typedef __attribute__((ext_vector_type(4))) float f32x4;

#define MARGIN 1.5e-4f
// PAD: shorts per LDS row. Row payload is 96 SHORTS (K'-chunk of 96), so PAD
// must be >= 96. 104 (= 208 B, 16B-aligned) is the R2-proven stride.
// R3's PAD=56 overlapped rows -> corrupted LDS -> absmax 512 failure.
#define PAD 104

// ---------------------------------------------------------------------------
// bf16 RNE split: x = hi + lo + O(2^-18 x)   (validated R1/R2)
// ---------------------------------------------------------------------------
__device__ __forceinline__ void bsplit(float x, unsigned short& h, unsigned short& l) {
    unsigned int u = __float_as_uint(x);
    unsigned int r = u + 0x7fffu + ((u >> 16) & 1u);
    h = (unsigned short)(r >> 16);
    float hf = __uint_as_float(((unsigned int)h) << 16);
    float res = x - hf;
    unsigned int u2 = __float_as_uint(res);
    unsigned int r2 = u2 + 0x7fffu + ((u2 >> 16) & 1u);
    l = (unsigned short)(r2 >> 16);
}

// ---------------------------------------------------------------------------
// wsq[k] = sum_d W[k][d]^2, fp64 accumulated, rounded once to fp32.
// ---------------------------------------------------------------------------
__global__ __launch_bounds__(256) void wsq_kernel(const float* __restrict__ W,
                                                  float* __restrict__ wsq) {
    int k = blockIdx.x * blockDim.x + threadIdx.x;
    if (k >= NK) return;
    const float4* row = (const float4*)(W + (size_t)k * DD);
    double s = 0.0;
    #pragma unroll 8
    for (int i = 0; i < DD / 4; ++i) {
        float4 v = row[i];
        s += (double)v.x * v.x + (double)v.y * v.y + (double)v.z * v.z + (double)v.w * v.w;
    }
    wsq[k] = (float)s;
}

// ---------------------------------------------------------------------------
// Wpp[(c*512 + k)*96]: bf16-split W in MFMA slot order (wh, wl, wh) per d.
// Chunk c covers d = c*32 .. c*32+31 -> 96 k'-slots. grid 8 x 512 threads.
// ---------------------------------------------------------------------------
__global__ __launch_bounds__(512) void convw_kernel(const float* __restrict__ W,
                                                    unsigned short* __restrict__ Wpp) {
    const int c = blockIdx.x;   // 0..7
    const int k = threadIdx.x;  // 0..511
    const int d0 = c * 32;

    float w[32];
    const float4* src4 = (const float4*)(W + (size_t)k * DD + d0);
    #pragma unroll
    for (int q = 0; q < 8; ++q) {
        float4 v = src4[q];
        w[4 * q + 0] = v.x; w[4 * q + 1] = v.y; w[4 * q + 2] = v.z; w[4 * q + 3] = v.w;
    }
    __align__(16) unsigned short o[96];
    #pragma unroll
    for (int j = 0; j < 32; ++j) {
        unsigned short h, l;
        bsplit(w[j], h, l);
        o[3 * j + 0] = h;
        o[3 * j + 1] = l;
        o[3 * j + 2] = h;
    }
    unsigned short* dst = Wpp + ((size_t)c * 512 + k) * 96;
    #pragma unroll
    for (int j = 0; j < 12; ++j) ((int4*)dst)[j] = ((const int4*)o)[j];
}

__global__ void zero_cnt(int* cnt) {
    if (threadIdx.x == 0 && blockIdx.x == 0) *cnt = 0;
}

// ---------------------------------------------------------------------------
// Phase 1: block = 128 t x 256 codes (h = bx&1 picks code half). 256 threads,
// 4 waves of 64t x 128k (4x8 tiles of 16x16x32_bf16). Z split ONCE per chunk.
// Emits per (t, h): (q1, q2, i1) after the reference rounding chain.
// ---------------------------------------------------------------------------
__global__ __launch_bounds__(256, 2) void vq_phase1(const float* __restrict__ Z,
                                                    const unsigned short* __restrict__ Wpp,
                                                    const float* __restrict__ wsq,
                                                    float* __restrict__ gq1,
                                                    float* __restrict__ gq2,
                                                    int* __restrict__ gi1) {
    __shared__ __align__(16) short As[128 * PAD];  // 26624 B
    __shared__ __align__(16) short Bs[256 * PAD];  // 53248 B  (total 79872 B -> 2 blk/CU)

    const int tid  = threadIdx.x;
    const int wave = tid >> 6;
    const int lane = tid & 63;
    const int lm   = lane & 15;
    const int lq   = lane >> 4;
    const int mw   = wave & 1;   // t half (64)
    const int nw   = wave >> 1;  // k half within the 256 (0..1 -> 128 each)

    const int bx = blockIdx.x;
    const int h  = bx & 1;       // code half: 0 -> k 0..255, 1 -> k 256..511
    const int tl = bx >> 1;
    const int b  = tl >> 5;
    const int t0 = (tl & 31) * 128;

    const int t_l = tid & 127;
    const int dg  = tid >> 7;    // 0..1, each covers 16 d per chunk

    const float* zcol = Z + (size_t)b * DD * NT + t0 + t_l;

    f32x4 acc[4][8];
    #pragma unroll
    for (int mt = 0; mt < 4; ++mt)
        #pragma unroll
        for (int nt = 0; nt < 8; ++nt)
            acc[mt][nt] = (f32x4){0.f, 0.f, 0.f, 0.f};

    double zacc = 0.0;

    for (int c = 0; c < 8; ++c) {
        const int d0 = c * 32;
        __syncthreads();

        // ---- A staging: 16 z loads (coalesced over t_l), fp64 zsq, split+pack
        {
            float zv[16];
            #pragma unroll
            for (int j = 0; j < 16; ++j)
                zv[j] = zcol[(size_t)(d0 + dg * 16 + j) * NT];
            #pragma unroll
            for (int j = 0; j < 16; ++j)
                zacc = fma((double)zv[j], (double)zv[j], zacc);

            __align__(16) unsigned int u[24];
            #pragma unroll
            for (int p = 0; p < 8; ++p) {
                int j = 2 * p;
                unsigned short h0, l0, h1, l1;
                bsplit(zv[j], h0, l0);
                bsplit(zv[j + 1], h1, l1);
                u[3 * p + 0] = (unsigned int)h0 | ((unsigned int)h0 << 16);
                u[3 * p + 1] = (unsigned int)l0 | ((unsigned int)h1 << 16);
                u[3 * p + 2] = (unsigned int)h1 | ((unsigned int)l1 << 16);
            }
            int4* dst = (int4*)&As[t_l * PAD + dg * 48];
            #pragma unroll
            for (int q = 0; q < 6; ++q) dst[q] = ((const int4*)u)[q];
        }
        // ---- B staging: pure int4 copies from Wpp (row = code h*256 + tid)
        {
            const unsigned short* src = Wpp + ((size_t)c * 512 + h * 256 + tid) * 96;
            int4 v[12];
            #pragma unroll
            for (int j = 0; j < 12; ++j) v[j] = ((const int4*)src)[j];
            int4* bd = (int4*)&Bs[tid * PAD];
            #pragma unroll
            for (int j = 0; j < 12; ++j) bd[j] = v[j];
        }
        __syncthreads();

        // ---- MFMA: 3 K-steps of 32
        #pragma unroll
        for (int ks = 0; ks < 3; ++ks) {
            bf16x8 a[4], bb[8];
            #pragma unroll
            for (int mt = 0; mt < 4; ++mt)
                a[mt] = *(const bf16x8*)&As[(mw * 64 + mt * 16 + lm) * PAD + ks * 32 + lq * 8];
            #pragma unroll
            for (int nt = 0; nt < 8; ++nt)
                bb[nt] = *(const bf16x8*)&Bs[(nw * 128 + nt * 16 + lm) * PAD + ks * 32 + lq * 8];
            #pragma unroll
            for (int mt = 0; mt < 4; ++mt)
                #pragma unroll
                for (int nt = 0; nt < 8; ++nt)
                    acc[mt][nt] = __builtin_amdgcn_mfma_f32_16x16x32_bf16(
                        a[mt], bb[nt], acc[mt][nt], 0, 0, 0);
        }
    }

    // ---- epilogue: zsq reduce (fp64 -> fp32 once), chain, per-t top-2
    __syncthreads();
    double* zred = (double*)As;
    zred[dg * 128 + t_l] = zacc;
    __syncthreads();
    float* zf = (float*)Bs;
    if (tid < 128) zf[tid] = (float)(zred[tid] + zred[128 + tid]);
    __syncthreads();

    float wq[8];
    #pragma unroll
    for (int nt = 0; nt < 8; ++nt)
        wq[nt] = wsq[h * 256 + nw * 128 + nt * 16 + lm];
    const int kbase = h * 256 + nw * 128 + lm;

    float* cb1 = (float*)As;          // [128][2]
    float* cb2 = cb1 + 256;
    int*   cbi = (int*)(cb2 + 256);

    #pragma unroll
    for (int mt = 0; mt < 4; ++mt) {
        #pragma unroll
        for (int r = 0; r < 4; ++r) {
            float zz = zf[mw * 64 + mt * 16 + lq * 4 + r];
            float q1 = INFINITY, q2 = INFINITY;
            int i1 = 0x7fffffff;
            #pragma unroll
            for (int nt = 0; nt < 8; ++nt) {
                float dist = __fadd_rn(__fsub_rn(zz, __fmul_rn(2.0f, acc[mt][nt][r])), wq[nt]);
                int kk = kbase + nt * 16;
                if (dist < q1 || (dist == q1 && kk < i1)) { q2 = q1; q1 = dist; i1 = kk; }
                else if (dist < q2) q2 = dist;
            }
            #pragma unroll
            for (int mk = 1; mk <= 8; mk <<= 1) {
                float o1 = __shfl_xor(q1, mk);
                float o2 = __shfl_xor(q2, mk);
                int   oi = __shfl_xor(i1, mk);
                if (o1 < q1 || (o1 == q1 && oi < i1)) { q2 = fminf(q1, o2); q1 = o1; i1 = oi; }
                else { q2 = fminf(o1, q2); }
            }
            if (lm == 0) {
                int m = mw * 64 + mt * 16 + lq * 4 + r;
                cb1[m * 2 + nw] = q1;
                cb2[m * 2 + nw] = q2;
                cbi[m * 2 + nw] = i1;
            }
        }
    }
    __syncthreads();
    if (tid < 128) {
        float a1 = cb1[tid * 2],     a2 = cb2[tid * 2];     int ai = cbi[tid * 2];
        float b1 = cb1[tid * 2 + 1], b2 = cb2[tid * 2 + 1]; int bi = cbi[tid * 2 + 1];
        float q1, q2; int i1;
        if (b1 < a1 || (b1 == a1 && bi < ai)) { q1 = b1; i1 = bi; q2 = fminf(a1, b2); }
        else { q1 = a1; i1 = ai; q2 = fminf(b1, a2); }
        size_t bt = (size_t)b * NT + t0 + tid;
        gq1[bt * 2 + h] = q1;
        gq2[bt * 2 + h] = q2;
        gi1[bt * 2 + h] = i1;
    }
}

// ---------------------------------------------------------------------------
// Merge halves, write approx argmin, compact near-ties into a list.
// ---------------------------------------------------------------------------
__global__ __launch_bounds__(256) void vq_merge(const float* __restrict__ gq1,
                                                const float* __restrict__ gq2,
                                                const int* __restrict__ gi1,
                                                int* __restrict__ out,
                                                int* __restrict__ list,
                                                int* __restrict__ cnt) {
    const int bt = blockIdx.x * 256 + threadIdx.x;
    float a1 = gq1[(size_t)bt * 2],     a2 = gq2[(size_t)bt * 2];     int ai = gi1[(size_t)bt * 2];
    float b1 = gq1[(size_t)bt * 2 + 1], b2 = gq2[(size_t)bt * 2 + 1]; int bi = gi1[(size_t)bt * 2 + 1];
    float q1, q2; int i1;
    if (b1 < a1 || (b1 == a1 && bi < ai)) { q1 = b1; i1 = bi; q2 = fminf(a1, b2); }
    else { q1 = a1; i1 = ai; q2 = fminf(b1, a2); }
    out[bt] = i1;
    if (q2 - q1 <= MARGIN) {
        int idx = atomicAdd(cnt, 1);
        list[idx] = bt;
    }
}

// ---------------------------------------------------------------------------
// Exact recompute for flagged t's, 8 items per block; W streamed once per
// group, 8 interleaved exact fmaf chains (ascending d -- R1-validated order).
// ---------------------------------------------------------------------------
__global__ __launch_bounds__(256) void vq_fix(const float* __restrict__ Z,
                                              const float* __restrict__ W,
                                              const float* __restrict__ wsq,
                                              const int* __restrict__ list,
                                              const int* __restrict__ cnt,
                                              int* __restrict__ out) {
    __shared__ float  Zs[8][256];
    __shared__ double pz[8][32];
    __shared__ float  zsqs[8];
    __shared__ int    bts[8];
    __shared__ float  rv[8][4];
    __shared__ int    ri[8][4];

    const int n    = *cnt;
    const int tid  = threadIdx.x;
    const int lane = tid & 63;
    const int wv   = tid >> 6;

    for (int base = blockIdx.x * 8; base < n; base += gridDim.x * 8) {
        const int m = (n - base < 8) ? (n - base) : 8;
        __syncthreads();   // previous iteration fully consumed
        if (tid < 8) bts[tid] = list[base + ((tid < m) ? tid : 0)];
        __syncthreads();

        #pragma unroll
        for (int i = 0; i < 8; ++i) {
            if (i < m) {
                int bt = bts[i];
                int bb = bt >> 12, t = bt & 4095;
                Zs[i][tid] = Z[(size_t)bb * DD * NT + (size_t)tid * NT + t];
            }
        }
        __syncthreads();

        // zsq partials: thread (i = tid>>5, seg = tid&31) sums d = seg*8..+8
        {
            int i = tid >> 5, seg = tid & 31;
            double s = 0.0;
            #pragma unroll
            for (int j = 0; j < 8; ++j) {
                double zz = (double)Zs[i][seg * 8 + j];
                s = fma(zz, zz, s);
            }
            pz[i][seg] = s;
        }
        __syncthreads();
        if (tid < 8) {
            double s = 0.0;
            #pragma unroll
            for (int j = 0; j < 32; ++j) s += pz[tid][j];
            zsqs[tid] = (float)s;
        }
        __syncthreads();

        // exact dists for k = tid, tid+256 across all 8 items
        float da[2][8];
        #pragma unroll
        for (int rr = 0; rr < 2; ++rr) {
            int k = tid + rr * 256;
            const float4* wr = (const float4*)(W + (size_t)k * DD);
            float a8[8];
            #pragma unroll
            for (int i = 0; i < 8; ++i) a8[i] = 0.f;
            for (int q = 0; q < 64; ++q) {
                float4 w4 = wr[q];
                #pragma unroll
                for (int i = 0; i < 8; ++i) {
                    a8[i] = fmaf(Zs[i][4 * q + 0], w4.x, a8[i]);
                    a8[i] = fmaf(Zs[i][4 * q + 1], w4.y, a8[i]);
                    a8[i] = fmaf(Zs[i][4 * q + 2], w4.z, a8[i]);
                    a8[i] = fmaf(Zs[i][4 * q + 3], w4.w, a8[i]);
                }
            }
            float wqv = wsq[k];
            #pragma unroll
            for (int i = 0; i < 8; ++i)
                da[rr][i] = __fadd_rn(__fsub_rn(zsqs[i], __fmul_rn(2.0f, a8[i])), wqv);
        }

        // per-item argmin over 512
        #pragma unroll
        for (int i = 0; i < 8; ++i) {
            float v = da[0][i]; int ix = tid;
            if (da[1][i] < v) { v = da[1][i]; ix = tid + 256; }
            #pragma unroll
            for (int mk = 1; mk <= 32; mk <<= 1) {
                float ov = __shfl_xor(v, mk);
                int   oi = __shfl_xor(ix, mk);
                if (ov < v || (ov == v && oi < ix)) { v = ov; ix = oi; }
            }
            if (lane == 0) { rv[i][wv] = v; ri[i][wv] = ix; }
        }
        __syncthreads();
        if (tid < 8 && tid < m) {
            float v = INFINITY; int ix = 0x7fffffff;
            #pragma unroll
            for (int w = 0; w < 4; ++w) {
                if (rv[tid][w] < v || (rv[tid][w] == v && ri[tid][w] < ix)) {
                    v = rv[tid][w]; ix = ri[tid][w];
                }
            }
            out[bts[tid]] = ix;
        }
    }
}

// ---------------------------------------------------------------------------
// Fallback (R1 kernel) if ws is too small.
// ---------------------------------------------------------------------------
#define BT 128
#define BK 128
#define DCHUNK 32
#define NKC (NK / BK)
#define NDC (DD / DCHUNK)
#define WSTR (BK + 4)

__global__ __launch_bounds__(256) void vq_fallback(const float* __restrict__ Z,
                                                   const float* __restrict__ W,
                                                   const float* __restrict__ wsq_g,
                                                   int* __restrict__ out) {
    __shared__ __align__(16) float Zs[DCHUNK * BT];
    __shared__ __align__(16) float Ws[DCHUNK * WSTR];
    __shared__ float wsqs[NK];

    const int tid = threadIdx.x;
    const int tx  = tid & 15;
    const int ty  = tid >> 4;
    const int b   = blockIdx.y;
    const int t0  = blockIdx.x * BT;

    if (wsq_g) {
        wsqs[tid]       = wsq_g[tid];
        wsqs[tid + 256] = wsq_g[tid + 256];
    } else {
        for (int k = tid; k < NK; k += 256) {
            const float4* row = (const float4*)(W + (size_t)k * DD);
            double s = 0.0;
            for (int i = 0; i < DD / 4; ++i) {
                float4 v = row[i];
                s += (double)v.x * v.x + (double)v.y * v.y + (double)v.z * v.z + (double)v.w * v.w;
            }
            wsqs[k] = (float)s;
        }
    }

    const float* Zb = Z + (size_t)b * DD * NT + t0;

    float best[8]; int bidx[8];
    #pragma unroll
    for (int a = 0; a < 8; ++a) { best[a] = INFINITY; bidx[a] = 0x7fffffff; }
    double zsqd[8];
    #pragma unroll
    for (int a = 0; a < 8; ++a) zsqd[a] = 0.0;
    float zsqf[8];

    for (int kc = 0; kc < NKC; ++kc) {
        float acc[8][8];
        #pragma unroll
        for (int a = 0; a < 8; ++a)
            #pragma unroll
            for (int c = 0; c < 8; ++c) acc[a][c] = 0.f;

        for (int dc = 0; dc < NDC; ++dc) {
            const int d0 = dc * DCHUNK;
            __syncthreads();
            #pragma unroll
            for (int i = 0; i < 4; ++i) {
                int f  = tid + i * 256;
                int r  = f >> 5;
                int c4 = f & 31;
                float4 v = *(const float4*)(Zb + (size_t)(d0 + r) * NT + c4 * 4);
                *(float4*)(&Zs[r * BT + c4 * 4]) = v;
            }
            #pragma unroll
            for (int i = 0; i < 4; ++i) {
                int u  = tid + i * 256;
                int k  = u >> 3;
                int rg = u & 7;
                float4 v = *(const float4*)(W + (size_t)(kc * BK + k) * DD + d0 + rg * 4);
                Ws[(rg * 4 + 0) * WSTR + k] = v.x;
                Ws[(rg * 4 + 1) * WSTR + k] = v.y;
                Ws[(rg * 4 + 2) * WSTR + k] = v.z;
                Ws[(rg * 4 + 3) * WSTR + k] = v.w;
            }
            __syncthreads();
            #pragma unroll 4
            for (int d = 0; d < DCHUNK; ++d) {
                float4 z0 = *(const float4*)(&Zs[d * BT + ty * 8]);
                float4 z1 = *(const float4*)(&Zs[d * BT + ty * 8 + 4]);
                float4 w0 = *(const float4*)(&Ws[d * WSTR + tx * 8]);
                float4 w1 = *(const float4*)(&Ws[d * WSTR + tx * 8 + 4]);
                float za[8] = {z0.x, z0.y, z0.z, z0.w, z1.x, z1.y, z1.z, z1.w};
                float wa[8] = {w0.x, w0.y, w0.z, w0.w, w1.x, w1.y, w1.z, w1.w};
                if (kc == 0) {
                    #pragma unroll
                    for (int a = 0; a < 8; ++a)
                        zsqd[a] = fma((double)za[a], (double)za[a], zsqd[a]);
                }
                #pragma unroll
                for (int a = 0; a < 8; ++a)
                    #pragma unroll
                    for (int c = 0; c < 8; ++c)
                        acc[a][c] = fmaf(za[a], wa[c], acc[a][c]);
            }
        }
        if (kc == 0) {
            #pragma unroll
            for (int a = 0; a < 8; ++a) zsqf[a] = (float)zsqd[a];
        }
        #pragma unroll
        for (int c = 0; c < 8; ++c) {
            int   kg = kc * BK + tx * 8 + c;
            float wqv = wsqs[kg];
            #pragma unroll
            for (int a = 0; a < 8; ++a) {
                float c2   = __fmul_rn(2.0f, acc[a][c]);
                float s    = __fsub_rn(zsqf[a], c2);
                float dist = __fadd_rn(s, wqv);
                if (dist < best[a] || (dist == best[a] && kg < bidx[a])) {
                    best[a] = dist; bidx[a] = kg;
                }
            }
        }
    }
    __syncthreads();
    float* redv = Zs;
    int*   redi = (int*)Ws;
    #pragma unroll
    for (int a = 0; a < 8; ++a) {
        int tl2 = ty * 8 + a;
        redv[tl2 * 16 + tx] = best[a];
        redi[tl2 * 16 + tx] = bidx[a];
    }
    __syncthreads();
    if (tid < BT) {
        float bv = INFINITY; int bi = 0x7fffffff;
        #pragma unroll
        for (int j = 0; j < 16; ++j) {
            float v = redv[tid * 16 + j];
            int   i = redi[tid * 16 + j];
            if (v < bv || (v == bv && i < bi)) { bv = v; bi = i; }
        }
        out[(size_t)b * NT + t0 + tid] = bi;
    }
}

extern "C" void kernel_launch(void* const* d_in, const int* in_sizes, int n_in,
                              void* d_out, int out_size, void* d_ws, size_t ws_size,
                              hipStream_t stream) {
    const float* Z = (const float*)d_in[0];   // [B, D, T]
    const float* W = (const float*)d_in[1];   // [K, D]
    int* out = (int*)d_out;                   // [B, T]

    // ws layout
    const size_t OFF_WSQ  = 0;                       // 512 f32
    const size_t OFF_CNT  = 2048;                    // 1 int
    const size_t OFF_LIST = 4096;                    // 131072 int
    const size_t OFF_WPP  = OFF_LIST + 524288;       // 786432 B
    const size_t OFF_GQ1  = OFF_WPP + 786432;        // 262144 f32
    const size_t OFF_GQ2  = OFF_GQ1 + 1048576;
    const size_t OFF_GI1  = OFF_GQ2 + 1048576;
    const size_t NEED     = OFF_GI1 + 1048576;       // 4,460,544 B

    if (ws_size >= NEED) {
        float* wsq = (float*)((char*)d_ws + OFF_WSQ);
        int*   cnt = (int*)((char*)d_ws + OFF_CNT);
        int*   list = (int*)((char*)d_ws + OFF_LIST);
        unsigned short* wpp = (unsigned short*)((char*)d_ws + OFF_WPP);
        float* gq1 = (float*)((char*)d_ws + OFF_GQ1);
        float* gq2 = (float*)((char*)d_ws + OFF_GQ2);
        int*   gi1 = (int*)((char*)d_ws + OFF_GI1);

        wsq_kernel<<<dim3(2), dim3(256), 0, stream>>>(W, wsq);
        convw_kernel<<<dim3(8), dim3(512), 0, stream>>>(W, wpp);
        zero_cnt<<<dim3(1), dim3(64), 0, stream>>>(cnt);
        vq_phase1<<<dim3(2048), dim3(256), 0, stream>>>(Z, wpp, wsq, gq1, gq2, gi1);
        vq_merge<<<dim3(512), dim3(256), 0, stream>>>(gq1, gq2, gi1, out, list, cnt);
        vq_fix<<<dim3(1024), dim3(256), 0, stream>>>(Z, W, wsq, list, cnt, out);
    } else {
        float* wsq = nullptr;
        if (ws_size >= NK * sizeof(float)) {
            wsq = (float*)d_ws;
            wsq_kernel<<<dim3(2), dim3(256), 0, stream>>>(W, wsq);
        }
        vq_fallback<<<dim3(NT / BT, NB), dim3(256), 0, stream>>>(Z, W, wsq, out);
    }
}

// Round 5
// 391.397 us; speedup vs baseline: 1.7497x; 1.0390x over previous
//
#include <hip/hip_runtime.h>
#include <math.h>

#define NK 512
#define DD 256
#define NB 32
#define NT 4096

typedef __attribute__((ext_vector_type(8))) _Float16 f16x8;
typedef __attribute__((ext_vector_type(4))) float f32x4;

#define MARGIN 1.5e-4f
#define DCH 16      // d per chunk
#define NCH 16      // chunks (DD/DCH)
#define KPC 32      // K' slots per chunk (2 per d)
#define APAD 40     // shorts per LDS row (80 B = 20 dwords: period-8 bank rotation, 2-way = free)

__device__ __forceinline__ unsigned short f16bits(float x) {
    _Float16 h = (_Float16)x;           // v_cvt_f16_f32, RNE
    unsigned short s;
    __builtin_memcpy(&s, &h, 2);
    return s;
}

// ---------------------------------------------------------------------------
// Prep: blocks 0..15 build Wpp (f16 w*4096, duplicated per-d slot pair);
// block 16 computes wsq (fp64 -> fp32 once). One launch.
// Wpp layout: [(c*512 + k)*32] shorts, c = d-chunk, k = code.
// ---------------------------------------------------------------------------
__global__ __launch_bounds__(512) void prep_kernel(const float* __restrict__ W,
                                                   unsigned short* __restrict__ Wpp,
                                                   float* __restrict__ wsq) {
    const int bx = blockIdx.x;
    const int k  = threadIdx.x;   // 0..511
    if (bx < NCH) {
        const int d0 = bx * DCH;
        float w[16];
        const float4* src4 = (const float4*)(W + (size_t)k * DD + d0);
        #pragma unroll
        for (int q = 0; q < 4; ++q) {
            float4 v = src4[q];
            w[4 * q + 0] = v.x; w[4 * q + 1] = v.y; w[4 * q + 2] = v.z; w[4 * q + 3] = v.w;
        }
        __align__(16) unsigned int dw[16];
        #pragma unroll
        for (int j = 0; j < 16; ++j) {
            unsigned short s = f16bits(w[j] * 4096.0f);  // exact pow2 scale, then RNE
            dw[j] = (unsigned int)s | ((unsigned int)s << 16);  // (wh, wh) slot pair
        }
        unsigned short* dst = Wpp + ((size_t)bx * 512 + k) * 32;
        #pragma unroll
        for (int j = 0; j < 4; ++j) ((int4*)dst)[j] = ((const int4*)dw)[j];
    } else {
        const float4* row = (const float4*)(W + (size_t)k * DD);
        double s = 0.0;
        #pragma unroll 8
        for (int i = 0; i < DD / 4; ++i) {
            float4 v = row[i];
            s += (double)v.x * v.x + (double)v.y * v.y + (double)v.z * v.z + (double)v.w * v.w;
        }
        wsq[k] = (float)s;
    }
}

// ---------------------------------------------------------------------------
// Phase 1: block = 128 t x 256 codes (h = bx&1). 256 thr, 4 waves of 64x128.
// K' = 512 (f16 2-slot z, 1-slot w scaled 2^12), 16 chunks of 32 slots.
// Emits per (t,h): (q1, q2, i1) after the reference fp32 rounding chain.
// ---------------------------------------------------------------------------
__global__ __launch_bounds__(256, 2) void vq_phase1(const float* __restrict__ Z,
                                                    const unsigned short* __restrict__ Wpp,
                                                    const float* __restrict__ wsq,
                                                    float* __restrict__ gq1,
                                                    float* __restrict__ gq2,
                                                    int* __restrict__ gi1) {
    __shared__ __align__(16) short As[128 * APAD];  // 10240 B
    __shared__ __align__(16) short Bs[256 * APAD];  // 20480 B  (total ~31 KB)

    const int tid  = threadIdx.x;
    const int wave = tid >> 6;
    const int lane = tid & 63;
    const int lm   = lane & 15;
    const int lq   = lane >> 4;
    const int mw   = wave & 1;   // t half
    const int nw   = wave >> 1;  // k half of the 256

    const int bx = blockIdx.x;
    const int h  = bx & 1;
    const int tl = bx >> 1;
    const int b  = tl >> 5;
    const int t0 = (tl & 31) * 128;

    const int t_l = tid & 127;
    const int dg  = tid >> 7;    // 0..1, 8 d each per chunk

    const float* zcol = Z + (size_t)b * DD * NT + t0 + t_l;

    f32x4 acc[4][8];
    #pragma unroll
    for (int mt = 0; mt < 4; ++mt)
        #pragma unroll
        for (int nt = 0; nt < 8; ++nt)
            acc[mt][nt] = (f32x4){0.f, 0.f, 0.f, 0.f};

    double zacc = 0.0;

    for (int c = 0; c < NCH; ++c) {
        const int d0 = c * DCH;
        __syncthreads();

        // ---- A staging: 8 z loads (coalesced over t_l), fp64 zsq, f16 split
        {
            float zv[8];
            #pragma unroll
            for (int j = 0; j < 8; ++j)
                zv[j] = zcol[(size_t)(d0 + dg * 8 + j) * NT];
            #pragma unroll
            for (int j = 0; j < 8; ++j)
                zacc = fma((double)zv[j], (double)zv[j], zacc);

            __align__(16) unsigned int u[8];
            #pragma unroll
            for (int j = 0; j < 8; ++j) {
                _Float16 zh = (_Float16)zv[j];
                float rz = zv[j] - (float)zh;     // exact (Sterbenz)
                unsigned short hs, ls;
                __builtin_memcpy(&hs, &zh, 2);
                ls = f16bits(rz);
                u[j] = (unsigned int)hs | ((unsigned int)ls << 16);  // (zh, zl)
            }
            int4* dst = (int4*)&As[t_l * APAD + dg * 16];
            dst[0] = ((const int4*)u)[0];
            dst[1] = ((const int4*)u)[1];
        }
        // ---- B staging: 4 int4 from Wpp (row = code h*256 + tid)
        {
            const unsigned short* src = Wpp + ((size_t)c * 512 + h * 256 + tid) * 32;
            int4 v0 = ((const int4*)src)[0];
            int4 v1 = ((const int4*)src)[1];
            int4 v2 = ((const int4*)src)[2];
            int4 v3 = ((const int4*)src)[3];
            int4* bd = (int4*)&Bs[tid * APAD];
            bd[0] = v0; bd[1] = v1; bd[2] = v2; bd[3] = v3;
        }
        __syncthreads();

        // ---- MFMA: one K'=32 step per chunk
        f16x8 a[4], bb[8];
        #pragma unroll
        for (int mt = 0; mt < 4; ++mt)
            a[mt] = *(const f16x8*)&As[(mw * 64 + mt * 16 + lm) * APAD + lq * 8];
        #pragma unroll
        for (int nt = 0; nt < 8; ++nt)
            bb[nt] = *(const f16x8*)&Bs[(nw * 128 + nt * 16 + lm) * APAD + lq * 8];
        #pragma unroll
        for (int mt = 0; mt < 4; ++mt)
            #pragma unroll
            for (int nt = 0; nt < 8; ++nt)
                acc[mt][nt] = __builtin_amdgcn_mfma_f32_16x16x32_f16(
                    a[mt], bb[nt], acc[mt][nt], 0, 0, 0);
    }

    // ---- epilogue: zsq reduce (fp64 -> fp32 once), chain, per-t top-2
    __syncthreads();
    double* zred = (double*)As;
    zred[dg * 128 + t_l] = zacc;
    __syncthreads();
    float* zf = (float*)Bs;
    if (tid < 128) zf[tid] = (float)(zred[tid] + zred[128 + tid]);
    __syncthreads();

    float wq[8];
    #pragma unroll
    for (int nt = 0; nt < 8; ++nt)
        wq[nt] = wsq[h * 256 + nw * 128 + nt * 16 + lm];
    const int kbase = h * 256 + nw * 128 + lm;

    float* cb1 = (float*)As;          // [128][2]
    float* cb2 = cb1 + 256;
    int*   cbi = (int*)(cb2 + 256);

    #pragma unroll
    for (int mt = 0; mt < 4; ++mt) {
        #pragma unroll
        for (int r = 0; r < 4; ++r) {
            float zz = zf[mw * 64 + mt * 16 + lq * 4 + r];
            float q1 = INFINITY, q2 = INFINITY;
            int i1 = 0x7fffffff;
            #pragma unroll
            for (int nt = 0; nt < 8; ++nt) {
                // acc holds cross*2^12; fl(2*cross) = acc * 2^-11 (exact pow2)
                float c2   = __fmul_rn(acc[mt][nt][r], 4.8828125e-4f);
                float dist = __fadd_rn(__fsub_rn(zz, c2), wq[nt]);
                int kk = kbase + nt * 16;
                if (dist < q1 || (dist == q1 && kk < i1)) { q2 = q1; q1 = dist; i1 = kk; }
                else if (dist < q2) q2 = dist;
            }
            #pragma unroll
            for (int mk = 1; mk <= 8; mk <<= 1) {
                float o1 = __shfl_xor(q1, mk);
                float o2 = __shfl_xor(q2, mk);
                int   oi = __shfl_xor(i1, mk);
                if (o1 < q1 || (o1 == q1 && oi < i1)) { q2 = fminf(q1, o2); q1 = o1; i1 = oi; }
                else { q2 = fminf(o1, q2); }
            }
            if (lm == 0) {
                int m = mw * 64 + mt * 16 + lq * 4 + r;
                cb1[m * 2 + nw] = q1;
                cb2[m * 2 + nw] = q2;
                cbi[m * 2 + nw] = i1;
            }
        }
    }
    __syncthreads();
    if (tid < 128) {
        float a1 = cb1[tid * 2],     a2 = cb2[tid * 2];     int ai = cbi[tid * 2];
        float b1 = cb1[tid * 2 + 1], b2 = cb2[tid * 2 + 1]; int bi = cbi[tid * 2 + 1];
        float q1, q2; int i1;
        if (b1 < a1 || (b1 == a1 && bi < ai)) { q1 = b1; i1 = bi; q2 = fminf(a1, b2); }
        else { q1 = a1; i1 = ai; q2 = fminf(b1, a2); }
        size_t bt = (size_t)b * NT + t0 + tid;
        gq1[bt * 2 + h] = q1;
        gq2[bt * 2 + h] = q2;
        gi1[bt * 2 + h] = i1;
    }
}

// ---------------------------------------------------------------------------
// Fused merge + exact fix: each block merges its 256 bt's, writes approx
// argmin, collects near-ties into an LDS list, then recomputes them exactly
// (identical fp32 chain / fmaf order as the R1-validated kernel).
// ---------------------------------------------------------------------------
__global__ __launch_bounds__(256) void vq_fixmerge(const float* __restrict__ Z,
                                                   const float* __restrict__ W,
                                                   const float* __restrict__ wsq,
                                                   const float* __restrict__ gq1,
                                                   const float* __restrict__ gq2,
                                                   const int* __restrict__ gi1,
                                                   int* __restrict__ out) {
    __shared__ __align__(16) float Zs[8][256];
    __shared__ double pz[8][32];
    __shared__ float  zsqs[8];
    __shared__ int    bts[8];
    __shared__ float  rv[8][4];
    __shared__ int    ri[8][4];
    __shared__ int    lcnt;
    __shared__ int    llist[256];

    const int tid  = threadIdx.x;
    const int lane = tid & 63;
    const int wv   = tid >> 6;
    const int bt   = blockIdx.x * 256 + tid;

    if (tid == 0) lcnt = 0;
    __syncthreads();

    // ---- merge the two code halves
    {
        float a1 = gq1[(size_t)bt * 2],     a2 = gq2[(size_t)bt * 2];     int ai = gi1[(size_t)bt * 2];
        float b1 = gq1[(size_t)bt * 2 + 1], b2 = gq2[(size_t)bt * 2 + 1]; int bi = gi1[(size_t)bt * 2 + 1];
        float q1, q2; int i1;
        if (b1 < a1 || (b1 == a1 && bi < ai)) { q1 = b1; i1 = bi; q2 = fminf(a1, b2); }
        else { q1 = a1; i1 = ai; q2 = fminf(b1, a2); }
        out[bt] = i1;
        if (q2 - q1 <= MARGIN) {
            int p = atomicAdd(&lcnt, 1);
            llist[p] = bt;
        }
    }
    __syncthreads();
    const int n = lcnt;

    for (int base = 0; base < n; base += 8) {
        const int m = (n - base < 8) ? (n - base) : 8;
        __syncthreads();
        if (tid < 8) bts[tid] = llist[base + ((tid < m) ? tid : 0)];
        __syncthreads();

        #pragma unroll
        for (int i = 0; i < 8; ++i) {
            if (i < m) {
                int tb = bts[i];
                int bb = tb >> 12, t = tb & 4095;
                Zs[i][tid] = Z[(size_t)bb * DD * NT + (size_t)tid * NT + t];
            }
        }
        __syncthreads();

        {
            int i = tid >> 5, seg = tid & 31;
            double s = 0.0;
            #pragma unroll
            for (int j = 0; j < 8; ++j) {
                double zz = (double)Zs[i][seg * 8 + j];
                s = fma(zz, zz, s);
            }
            pz[i][seg] = s;
        }
        __syncthreads();
        if (tid < 8) {
            double s = 0.0;
            #pragma unroll
            for (int j = 0; j < 32; ++j) s += pz[tid][j];
            zsqs[tid] = (float)s;
        }
        __syncthreads();

        float da[2][8];
        #pragma unroll
        for (int rr = 0; rr < 2; ++rr) {
            int k = tid + rr * 256;
            const float4* wr = (const float4*)(W + (size_t)k * DD);
            float a8[8];
            #pragma unroll
            for (int i = 0; i < 8; ++i) a8[i] = 0.f;
            for (int q = 0; q < 64; ++q) {
                float4 w4 = wr[q];
                #pragma unroll
                for (int i = 0; i < 8; ++i) {
                    float4 z4 = *(const float4*)&Zs[i][4 * q];   // LDS broadcast
                    a8[i] = fmaf(z4.x, w4.x, a8[i]);
                    a8[i] = fmaf(z4.y, w4.y, a8[i]);
                    a8[i] = fmaf(z4.z, w4.z, a8[i]);
                    a8[i] = fmaf(z4.w, w4.w, a8[i]);
                }
            }
            float wqv = wsq[k];
            #pragma unroll
            for (int i = 0; i < 8; ++i)
                da[rr][i] = __fadd_rn(__fsub_rn(zsqs[i], __fmul_rn(2.0f, a8[i])), wqv);
        }

        #pragma unroll
        for (int i = 0; i < 8; ++i) {
            float v = da[0][i]; int ix = tid;
            if (da[1][i] < v) { v = da[1][i]; ix = tid + 256; }
            #pragma unroll
            for (int mk = 1; mk <= 32; mk <<= 1) {
                float ov = __shfl_xor(v, mk);
                int   oi = __shfl_xor(ix, mk);
                if (ov < v || (ov == v && oi < ix)) { v = ov; ix = oi; }
            }
            if (lane == 0) { rv[i][wv] = v; ri[i][wv] = ix; }
        }
        __syncthreads();
        if (tid < 8 && tid < m) {
            float v = INFINITY; int ix = 0x7fffffff;
            #pragma unroll
            for (int w = 0; w < 4; ++w) {
                if (rv[tid][w] < v || (rv[tid][w] == v && ri[tid][w] < ix)) {
                    v = rv[tid][w]; ix = ri[tid][w];
                }
            }
            out[bts[tid]] = ix;
        }
    }
}

// ---------------------------------------------------------------------------
// Fallback (R1 kernel) if ws is too small.
// ---------------------------------------------------------------------------
#define BT 128
#define BK 128
#define DCHUNK 32
#define NKC (NK / BK)
#define NDC (DD / DCHUNK)
#define WSTR (BK + 4)

__global__ __launch_bounds__(256) void vq_fallback(const float* __restrict__ Z,
                                                   const float* __restrict__ W,
                                                   int* __restrict__ out) {
    __shared__ __align__(16) float Zs[DCHUNK * BT];
    __shared__ __align__(16) float Ws[DCHUNK * WSTR];
    __shared__ float wsqs[NK];

    const int tid = threadIdx.x;
    const int tx  = tid & 15;
    const int ty  = tid >> 4;
    const int b   = blockIdx.y;
    const int t0  = blockIdx.x * BT;

    for (int k = tid; k < NK; k += 256) {
        const float4* row = (const float4*)(W + (size_t)k * DD);
        double s = 0.0;
        for (int i = 0; i < DD / 4; ++i) {
            float4 v = row[i];
            s += (double)v.x * v.x + (double)v.y * v.y + (double)v.z * v.z + (double)v.w * v.w;
        }
        wsqs[k] = (float)s;
    }

    const float* Zb = Z + (size_t)b * DD * NT + t0;

    float best[8]; int bidx[8];
    #pragma unroll
    for (int a = 0; a < 8; ++a) { best[a] = INFINITY; bidx[a] = 0x7fffffff; }
    double zsqd[8];
    #pragma unroll
    for (int a = 0; a < 8; ++a) zsqd[a] = 0.0;
    float zsqf[8];

    for (int kc = 0; kc < NKC; ++kc) {
        float acc[8][8];
        #pragma unroll
        for (int a = 0; a < 8; ++a)
            #pragma unroll
            for (int c = 0; c < 8; ++c) acc[a][c] = 0.f;

        for (int dc = 0; dc < NDC; ++dc) {
            const int d0 = dc * DCHUNK;
            __syncthreads();
            #pragma unroll
            for (int i = 0; i < 4; ++i) {
                int f  = tid + i * 256;
                int r  = f >> 5;
                int c4 = f & 31;
                float4 v = *(const float4*)(Zb + (size_t)(d0 + r) * NT + c4 * 4);
                *(float4*)(&Zs[r * BT + c4 * 4]) = v;
            }
            #pragma unroll
            for (int i = 0; i < 4; ++i) {
                int u  = tid + i * 256;
                int k  = u >> 3;
                int rg = u & 7;
                float4 v = *(const float4*)(W + (size_t)(kc * BK + k) * DD + d0 + rg * 4);
                Ws[(rg * 4 + 0) * WSTR + k] = v.x;
                Ws[(rg * 4 + 1) * WSTR + k] = v.y;
                Ws[(rg * 4 + 2) * WSTR + k] = v.z;
                Ws[(rg * 4 + 3) * WSTR + k] = v.w;
            }
            __syncthreads();
            #pragma unroll 4
            for (int d = 0; d < DCHUNK; ++d) {
                float4 z0 = *(const float4*)(&Zs[d * BT + ty * 8]);
                float4 z1 = *(const float4*)(&Zs[d * BT + ty * 8 + 4]);
                float4 w0 = *(const float4*)(&Ws[d * WSTR + tx * 8]);
                float4 w1 = *(const float4*)(&Ws[d * WSTR + tx * 8 + 4]);
                float za[8] = {z0.x, z0.y, z0.z, z0.w, z1.x, z1.y, z1.z, z1.w};
                float wa[8] = {w0.x, w0.y, w0.z, w0.w, w1.x, w1.y, w1.z, w1.w};
                if (kc == 0) {
                    #pragma unroll
                    for (int a = 0; a < 8; ++a)
                        zsqd[a] = fma((double)za[a], (double)za[a], zsqd[a]);
                }
                #pragma unroll
                for (int a = 0; a < 8; ++a)
                    #pragma unroll
                    for (int c = 0; c < 8; ++c)
                        acc[a][c] = fmaf(za[a], wa[c], acc[a][c]);
            }
        }
        if (kc == 0) {
            #pragma unroll
            for (int a = 0; a < 8; ++a) zsqf[a] = (float)zsqd[a];
        }
        #pragma unroll
        for (int c = 0; c < 8; ++c) {
            int   kg = kc * BK + tx * 8 + c;
            float wqv = wsqs[kg];
            #pragma unroll
            for (int a = 0; a < 8; ++a) {
                float c2   = __fmul_rn(2.0f, acc[a][c]);
                float s    = __fsub_rn(zsqf[a], c2);
                float dist = __fadd_rn(s, wqv);
                if (dist < best[a] || (dist == best[a] && kg < bidx[a])) {
                    best[a] = dist; bidx[a] = kg;
                }
            }
        }
    }
    __syncthreads();
    float* redv = Zs;
    int*   redi = (int*)Ws;
    #pragma unroll
    for (int a = 0; a < 8; ++a) {
        int tl2 = ty * 8 + a;
        redv[tl2 * 16 + tx] = best[a];
        redi[tl2 * 16 + tx] = bidx[a];
    }
    __syncthreads();
    if (tid < BT) {
        float bv = INFINITY; int bi = 0x7fffffff;
        #pragma unroll
        for (int j = 0; j < 16; ++j) {
            float v = redv[tid * 16 + j];
            int   i = redi[tid * 16 + j];
            if (v < bv || (v == bv && i < bi)) { bv = v; bi = i; }
        }
        out[(size_t)b * NT + t0 + tid] = bi;
    }
}

extern "C" void kernel_launch(void* const* d_in, const int* in_sizes, int n_in,
                              void* d_out, int out_size, void* d_ws, size_t ws_size,
                              hipStream_t stream) {
    const float* Z = (const float*)d_in[0];   // [B, D, T]
    const float* W = (const float*)d_in[1];   // [K, D]
    int* out = (int*)d_out;                   // [B, T]

    // ws layout
    const size_t OFF_WSQ = 0;                        // 512 f32
    const size_t OFF_WPP = 2048;                     // 512 KB
    const size_t OFF_GQ1 = OFF_WPP + 524288;
    const size_t OFF_GQ2 = OFF_GQ1 + 1048576;
    const size_t OFF_GI1 = OFF_GQ2 + 1048576;
    const size_t NEED    = OFF_GI1 + 1048576;        // 3,672,064 B

    if (ws_size >= NEED) {
        float* wsq = (float*)((char*)d_ws + OFF_WSQ);
        unsigned short* wpp = (unsigned short*)((char*)d_ws + OFF_WPP);
        float* gq1 = (float*)((char*)d_ws + OFF_GQ1);
        float* gq2 = (float*)((char*)d_ws + OFF_GQ2);
        int*   gi1 = (int*)((char*)d_ws + OFF_GI1);

        prep_kernel<<<dim3(NCH + 1), dim3(512), 0, stream>>>(W, wpp, wsq);
        vq_phase1<<<dim3(2048), dim3(256), 0, stream>>>(Z, wpp, wsq, gq1, gq2, gi1);
        vq_fixmerge<<<dim3(512), dim3(256), 0, stream>>>(Z, W, wsq, gq1, gq2, gi1, out);
    } else {
        vq_fallback<<<dim3(NT / BT, NB), dim3(256), 0, stream>>>(Z, W, out);
    }
}